// Round 6
// baseline (9336.062 us; speedup 1.0000x reference)
//
#include <hip/hip_runtime.h>
#include <stdint.h>

// Problem dims
#define NB 512   // batch N
#define NM 64    // rows of G
#define NT 32    // tx antennas (and scan steps)
#define NK 8     // symbol alphabet
#define NS 256   // MC samples

// JAX threefry_partitionable=True RNG verified bit-exact in round 1 (absmax 1.0).

__device__ __forceinline__ uint2 tf2x32(uint32_t k0, uint32_t k1, uint32_t x0, uint32_t x1) {
  uint32_t k2 = k0 ^ k1 ^ 0x1BD11BDAu;
#define TFRND(r) { x0 += x1; x1 = (x1 << (r)) | (x1 >> (32 - (r))); x1 ^= x0; }
  x0 += k0; x1 += k1;
  TFRND(13) TFRND(15) TFRND(26) TFRND(6)
  x0 += k1; x1 += k2 + 1u;
  TFRND(17) TFRND(29) TFRND(16) TFRND(24)
  x0 += k2; x1 += k0 + 2u;
  TFRND(13) TFRND(15) TFRND(26) TFRND(6)
  x0 += k0; x1 += k1 + 3u;
  TFRND(17) TFRND(29) TFRND(16) TFRND(24)
  x0 += k1; x1 += k2 + 4u;
  TFRND(13) TFRND(15) TFRND(26) TFRND(6)
  x0 += k2; x1 += k0 + 5u;
#undef TFRND
  return make_uint2(x0, x1);
}

// JAX uniform(minval=tiny, maxval=1) -> gumbel = -log(-log(u))
__device__ __forceinline__ float gumbel_from_bits(uint32_t bits) {
  const float TINY = 1.17549435e-38f;
  float f = __uint_as_float((bits >> 9) | 0x3f800000u) - 1.0f;
  float u = fmaxf(TINY, f + TINY);
  return -logf(-logf(u));
}

__global__ __launch_bounds__(256) void init_kernel(
    const float* __restrict__ log_qi, const float* __restrict__ G,
    const float* __restrict__ s2r, float* __restrict__ lq,
    float* __restrict__ sG, uint32_t* __restrict__ keys) {
  int i = blockIdx.x * 256 + threadIdx.x;
  if (i < NB * NM * NT) {
    int n = i >> 11;            // / (NM*NT = 2048)
    sG[i] = s2r[n] * G[i];      // exact f32 mul
  }
  if (i < NB * NT * NK) lq[i] = log_qi[i];
  if (i < NT) {
    // split foldlike: key_i = threefry2x32(parent, hi=0, lo=i)
    uint2 r = tf2x32(0u, 42u, 0u, (uint32_t)i);
    keys[2 * i] = r.x; keys[2 * i + 1] = r.y;
  }
}

// One thread per (s, n, t): 8 gumbels -> argmax -> biased symbol u8 = sym+7 = 2*argmax.
// Storage layout (n, s, t) so update_kernel reads coalesced per-n rows.
__global__ __launch_bounds__(256) void sample_kernel(
    const float* __restrict__ lq, const uint32_t* __restrict__ keys,
    uint8_t* __restrict__ symu, int xi) {
  int gid = blockIdx.x * 256 + threadIdx.x;       // = (s*NB + n)*NT + t  (threefry order)
  int t = gid & (NT - 1);
  int n = (gid >> 5) & (NB - 1);
  int s = gid >> 14;                              // / (NB*NT = 16384)
  uint32_t kA = keys[2 * xi], kB = keys[2 * xi + 1];
  const float* lrow = lq + (size_t)(n * NT + t) * NK;
  float l[NK];
#pragma unroll
  for (int k = 0; k < NK; ++k) l[k] = lrow[k];

  float best = -INFINITY; int bi = 0;
  uint32_t p = (uint32_t)gid << 3;                // flat index into (S,N,T,K) gumbel array
#pragma unroll
  for (int k = 0; k < NK; ++k) {
    uint2 r = tf2x32(kA, kB, 0u, p + (uint32_t)k);
    float g = gumbel_from_bits(r.x ^ r.y);
    float v = l[k] + g;
    if (v > best) { best = v; bi = k; }           // first-max tie-break like argmax
  }
  symu[((size_t)n * NS + s) * NT + t] = (uint8_t)(2 * bi);   // u = sym + 7
}

// Block per n: 1024 threads = (s in 0..255) x (mg in 0..3); thread handles 16 m's.
// Symbols stay PACKED in 8 u32 VGPRs (u8 = sym+7); converted per use with
// cvt_f32_ubyte + (-7.0f) -> products bit-identical to sg*sym. xi exclusion by
// inserting byte 7 (== symbol 0) once at load time (static-index cndmask loop,
// rule #20 safe). sg rows read as uniform ds_read_b128 (broadcast, no conflicts).
__global__ __launch_bounds__(1024, 8) void update_kernel(
    float* __restrict__ lq, const float* __restrict__ sG,
    const uint8_t* __restrict__ symu, const float* __restrict__ alpha_p, int xi) {
  __shared__ float sg_s[NM * NT];      // 8 KiB
  __shared__ double red[16][NK];       // 1 KiB
  __shared__ float lqrow[NT * NK];     // 1 KiB
  int n = blockIdx.x;
  int tid = threadIdx.x;
  int s = tid & (NS - 1);
  int mg = tid >> 8;                   // 0..3

  // stage sG row-block: 1024 threads x 8B, coalesced
  ((float2*)sg_s)[tid] = ((const float2*)(sG + (size_t)n * NM * NT))[tid];
  if (tid < NT * NK) lqrow[tid] = lq[(size_t)n * NT * NK + tid];

  // my sample row: 32 biased bytes, coalesced uint4 x2
  const uint4* sp = (const uint4*)(symu + ((size_t)n * NS + s) * NT);
  uint4 a = sp[0], b = sp[1];
  uint32_t w[8] = {a.x, a.y, a.z, a.w, b.x, b.y, b.z, b.w};
  {
    int jx = xi >> 2;
    uint32_t sh = (uint32_t)(8 * (xi & 3));
    uint32_t mask = 0xffu << sh, ins = 7u << sh;   // u=7 <=> symbol 0 (exact exclusion)
#pragma unroll
    for (int j = 0; j < 8; ++j)
      w[j] = (j == jx) ? ((w[j] & ~mask) | ins) : w[j];
  }
  __syncthreads();

  float lp[NK];
#pragma unroll
  for (int k = 0; k < NK; ++k) lp[k] = 0.0f;

  const float* sgp = sg_s + mg * 16 * NT;
  for (int mi = 0; mi < 16; ++mi) {
    const float4* row = (const float4*)(sgp + mi * NT);
    float base = 0.0f;
#pragma unroll
    for (int j = 0; j < 8; ++j) {
      float4 g4 = row[j];                               // uniform b128 (broadcast)
      float s0 = (float)( w[j]        & 0xffu) - 7.0f;  // cvt_f32_ubyte, exact ints
      float s1 = (float)((w[j] >>  8) & 0xffu) - 7.0f;
      float s2 = (float)((w[j] >> 16) & 0xffu) - 7.0f;
      float s3 = (float)( w[j] >> 24         ) - 7.0f;
      base = fmaf(g4.x, s0, base);
      base = fmaf(g4.y, s1, base);
      base = fmaf(g4.z, s2, base);
      base = fmaf(g4.w, s3, base);
    }
    float c = sgp[mi * NT + xi];
#pragma unroll
    for (int k = 0; k < NK; ++k) {
      float sk = (float)(2 * k - 7);
      float term = fmaf(c, sk, base);
      float z = 1.702f * term;
      // jax.nn.log_sigmoid(z) = min(z,0) - log1p(exp(-|z|))
      float e = expf(-fabsf(z));
      lp[k] += fminf(z, 0.0f) - log1pf(e);
    }
  }

  // reduce lp over all 1024 threads (f64)
  double v[NK];
#pragma unroll
  for (int k = 0; k < NK; ++k) v[k] = (double)lp[k];
#pragma unroll
  for (int off = 32; off >= 1; off >>= 1) {
#pragma unroll
    for (int k = 0; k < NK; ++k) v[k] += __shfl_down(v[k], off, 64);
  }
  int wave = tid >> 6, lane = tid & 63;
  if (lane == 0) {
#pragma unroll
    for (int k = 0; k < NK; ++k) red[wave][k] = v[k];
  }
  __syncthreads();
  if (tid < NK) {
    double sum = 0.0;
#pragma unroll
    for (int q = 0; q < 16; ++q) sum += red[q][tid];
    float ex = (float)(sum * (1.0 / 256.0));
    float alpha = *alpha_p;
    float oldv = lqrow[xi * NK + tid];
    lqrow[xi * NK + tid] = (1.0f - alpha) * oldv + alpha * ex;
  }
  __syncthreads();
  if (tid < NT * NK) {
    // per-(n,t) max shift over groups of NK=8 (exact; unchanged rows bit-exact)
    float vv = lqrow[tid];
    float mx = vv;
    mx = fmaxf(mx, __shfl_xor(mx, 1, 64));
    mx = fmaxf(mx, __shfl_xor(mx, 2, 64));
    mx = fmaxf(mx, __shfl_xor(mx, 4, 64));
    lq[(size_t)n * NT * NK + tid] = vv - mx;
  }
}

extern "C" void kernel_launch(void* const* d_in, const int* in_sizes, int n_in,
                              void* d_out, int out_size, void* d_ws, size_t ws_size,
                              hipStream_t stream) {
  const float* log_qi = (const float*)d_in[0];
  const float* G      = (const float*)d_in[1];
  const float* s2r    = (const float*)d_in[2];
  const float* alpha  = (const float*)d_in[3];
  float* lq = (float*)d_out;                       // lq working buffer IS the output
  char* ws = (char*)d_ws;
  float*    sG   = (float*)ws;                                   // 4 MiB
  uint8_t*  symu = (uint8_t*)(ws + (size_t)NB * NM * NT * 4);    // 4 MiB, layout (n,s,t)
  uint32_t* keys = (uint32_t*)(ws + (size_t)NB * NM * NT * 4 + (size_t)NS * NB * NT);

  init_kernel<<<4096, 256, 0, stream>>>(log_qi, G, s2r, lq, sG, keys);
  for (int xi = 0; xi < NT; ++xi) {
    sample_kernel<<<(NS * NB * NT) / 256, 256, 0, stream>>>(lq, keys, symu, xi);
    update_kernel<<<NB, 1024, 0, stream>>>(lq, sG, symu, alpha, xi);
  }
}

// Round 7
// 3924.217 us; speedup vs baseline: 2.3791x; 2.3791x over previous
//
#include <hip/hip_runtime.h>
#include <stdint.h>

// Problem dims
#define NB 512   // batch N
#define NM 64    // rows of G
#define NT 32    // tx antennas (and scan steps)
#define NK 8     // symbol alphabet
#define NS 256   // MC samples
#define LQP 9    // padded LDS row stride for lq (dwords): bank-conflict-free
#define SYP 36   // padded LDS row stride for sym (bytes): bank-conflict-free

// JAX threefry_partitionable=True RNG verified bit-exact in round 1 (absmax 1.0).
__device__ __forceinline__ uint2 tf2x32(uint32_t k0, uint32_t k1, uint32_t x0, uint32_t x1) {
  uint32_t k2 = k0 ^ k1 ^ 0x1BD11BDAu;
#define TFRND(r) { x0 += x1; x1 = (x1 << (r)) | (x1 >> (32 - (r))); x1 ^= x0; }
  x0 += k0; x1 += k1;
  TFRND(13) TFRND(15) TFRND(26) TFRND(6)
  x0 += k1; x1 += k2 + 1u;
  TFRND(17) TFRND(29) TFRND(16) TFRND(24)
  x0 += k2; x1 += k0 + 2u;
  TFRND(13) TFRND(15) TFRND(26) TFRND(6)
  x0 += k0; x1 += k1 + 3u;
  TFRND(17) TFRND(29) TFRND(16) TFRND(24)
  x0 += k1; x1 += k2 + 4u;
  TFRND(13) TFRND(15) TFRND(26) TFRND(6)
  x0 += k2; x1 += k0 + 5u;
#undef TFRND
  return make_uint2(x0, x1);
}

// JAX uniform(minval=tiny,maxval=1) -> gumbel = -log(-log(u)). libm logf: this is
// the bit-critical sampling path (round-1 proven) — do NOT fast-math this.
__device__ __forceinline__ float gumbel_from_bits(uint32_t bits) {
  const float TINY = 1.17549435e-38f;
  float f = __uint_as_float((bits >> 9) | 0x3f800000u) - 1.0f;
  float u = fmaxf(TINY, f + TINY);
  return -logf(-logf(u));
}

// One block per batch element n; all 32 scan steps fused, lq/sG/symbols in LDS.
// No min-waves in launch_bounds: round 6 showed forcing 8 waves/EU caps VGPR at
// 64 and the allocator then spills ~73 MB/dispatch to scratch. Let it take 128.
__global__ __launch_bounds__(1024) void mfs_fused(
    const float* __restrict__ log_qi, const float* __restrict__ G,
    const float* __restrict__ s2r, const float* __restrict__ alpha_p,
    float* __restrict__ lq_out) {
  __shared__ float sg[NM * NT];          // 8 KiB
  __shared__ float lqs[NT * LQP];        // padded 32x9 dwords
  __shared__ uint8_t symu[NS * SYP];     // padded 256x36 bytes (u8 = sym+7)
  __shared__ double red[16][NK];         // 1 KiB wave partials
  __shared__ uint32_t keys2[NT * 2];

  const int n = blockIdx.x;
  const int tid = threadIdx.x;

  {
    // sG row = sqrt_2rho[n] * G[n] (exact f32 mul), 2048 floats via float2/thread
    float s2v = s2r[n];
    float2 g2 = ((const float2*)(G + (size_t)n * NM * NT))[tid];
    ((float2*)sg)[tid] = make_float2(s2v * g2.x, s2v * g2.y);
  }
  if (tid < NT * NK) lqs[(tid >> 3) * LQP + (tid & 7)] = log_qi[(size_t)n * NT * NK + tid];
  if (tid < NT) {
    // split foldlike: key_i = threefry2x32(parent=(0,42), hi=0, lo=i)
    uint2 r = tf2x32(0u, 42u, 0u, (uint32_t)tid);
    keys2[2 * tid] = r.x; keys2[2 * tid + 1] = r.y;
  }
  __syncthreads();

  const float alpha = *alpha_p;
  const int t = tid & 31;            // sampling: antenna owned by this thread
  const int sgrp = tid >> 5;         // sampling: s-group 0..31
  const int ss = tid & 255;          // update: sample row
  const int mg = tid >> 8;           // update: m-group 0..3 (16 m's each)

  for (int xi = 0; xi < NT; ++xi) {
    // ---------- sample: 8 draws/thread, 8 gumbels each ----------
    uint32_t kA = keys2[2 * xi], kB = keys2[2 * xi + 1];
    float l[NK];
#pragma unroll
    for (int k = 0; k < NK; ++k) l[k] = lqs[t * LQP + k];   // stride-9: conflict-free
    for (int d = 0; d < 8; ++d) {
      int s = sgrp + (d << 5);
      uint32_t p = ((uint32_t)((s * NB + n) * NT + t)) << 3; // flat (S,N,T,K) index
      float best = -INFINITY; int bi = 0;
#pragma unroll
      for (int k = 0; k < NK; ++k) {
        uint2 r = tf2x32(kA, kB, 0u, p + (uint32_t)k);
        float v = l[k] + gumbel_from_bits(r.x ^ r.y);
        if (v > best) { best = v; bi = k; }                  // first-max tie-break
      }
      symu[s * SYP + t] = (uint8_t)(2 * bi);                 // u = sym + 7
    }
    __syncthreads();

    // ---------- update: thread = (sample ss, m-group mg) ----------
    uint32_t w[8];
#pragma unroll
    for (int j = 0; j < 8; ++j) w[j] = *(const uint32_t*)(symu + ss * SYP + 4 * j);
    {
      int jx = xi >> 2;
      uint32_t sh = (uint32_t)(8 * (xi & 3));
      uint32_t mask = 0xffu << sh, ins = 7u << sh;           // u=7 <=> symbol 0
#pragma unroll
      for (int j = 0; j < 8; ++j)
        w[j] = (j == jx) ? ((w[j] & ~mask) | ins) : w[j];    // static idx, cndmask
    }
    float lp[NK];
#pragma unroll
    for (int k = 0; k < NK; ++k) lp[k] = 0.0f;
    const float* sgp = sg + mg * 16 * NT;
    for (int mi = 0; mi < 16; ++mi) {
      const float4* row = (const float4*)(sgp + mi * NT);    // wave-uniform: broadcast
      float base = 0.0f;
#pragma unroll
      for (int j = 0; j < 8; ++j) {
        float4 g4 = row[j];
        float s0 = (float)( w[j]        & 0xffu) - 7.0f;     // exact int converts
        float s1 = (float)((w[j] >>  8) & 0xffu) - 7.0f;
        float s2 = (float)((w[j] >> 16) & 0xffu) - 7.0f;
        float s3 = (float)( w[j] >> 24         ) - 7.0f;
        base = fmaf(g4.x, s0, base);
        base = fmaf(g4.y, s1, base);
        base = fmaf(g4.z, s2, base);
        base = fmaf(g4.w, s3, base);
      }
      float c = sgp[mi * NT + xi];
#pragma unroll
      for (int k = 0; k < NK; ++k) {
        float term = fmaf(c, (float)(2 * k - 7), base);
        float z = 1.702f * term;
        // log_sigmoid(z) = min(z,0) - log1p(exp(-|z|)); fast intrinsics OK here:
        // round 6 proved ~1e-5 perturbations of ex_log_qi don't cascade (absmax
        // stayed exactly 1.0 across a reduction-order change). Error here ~1e-6.
        float az = fabsf(z);
        float e = __expf(-az);
        lp[k] += fminf(z, 0.0f) - __logf(1.0f + e);
      }
    }

    // reduction: IDENTICAL structure/order to round 6 (proven absmax 1.0)
    double v[NK];
#pragma unroll
    for (int k = 0; k < NK; ++k) v[k] = (double)lp[k];
#pragma unroll
    for (int off = 32; off >= 1; off >>= 1) {
#pragma unroll
      for (int k = 0; k < NK; ++k) v[k] += __shfl_down(v[k], off, 64);
    }
    int wave = tid >> 6, lane = tid & 63;
    if (lane == 0) {
#pragma unroll
      for (int k = 0; k < NK; ++k) red[wave][k] = v[k];
    }
    __syncthreads();
    if (tid < NK) {
      double sum = 0.0;
#pragma unroll
      for (int q = 0; q < 16; ++q) sum += red[q][tid];
      float ex = (float)(sum * (1.0 / 256.0));
      float oldv = lqs[xi * LQP + tid];
      lqs[xi * LQP + tid] = (1.0f - alpha) * oldv + alpha * ex;
    }
    __syncthreads();
    if (tid < NT * NK) {
      // per-row max shift (exact; settled rows have max==0 -> bit-exact no-op)
      int t2 = tid >> 3, k2 = tid & 7;
      float vv = lqs[t2 * LQP + k2];
      float mx = vv;
      mx = fmaxf(mx, __shfl_xor(mx, 1, 64));
      mx = fmaxf(mx, __shfl_xor(mx, 2, 64));
      mx = fmaxf(mx, __shfl_xor(mx, 4, 64));
      lqs[t2 * LQP + k2] = vv - mx;
    }
    __syncthreads();
  }

  if (tid < NT * NK)
    lq_out[(size_t)n * NT * NK + tid] = lqs[(tid >> 3) * LQP + (tid & 7)];
}

extern "C" void kernel_launch(void* const* d_in, const int* in_sizes, int n_in,
                              void* d_out, int out_size, void* d_ws, size_t ws_size,
                              hipStream_t stream) {
  const float* log_qi = (const float*)d_in[0];
  const float* G      = (const float*)d_in[1];
  const float* s2r    = (const float*)d_in[2];
  const float* alpha  = (const float*)d_in[3];
  float* lq = (float*)d_out;
  mfs_fused<<<NB, 1024, 0, stream>>>(log_qi, G, s2r, alpha, lq);
}

// Round 8
// 3717.428 us; speedup vs baseline: 2.5114x; 1.0556x over previous
//
#include <hip/hip_runtime.h>
#include <stdint.h>

// Problem dims
#define NB 512   // batch N
#define NM 64    // rows of G
#define NT 32    // tx antennas (and scan steps)
#define NK 8     // symbol alphabet
#define NS 256   // MC samples
#define LQP 9    // padded LDS row stride for lq (dwords)
#define SYP 36   // padded LDS row stride for sym (bytes)

// JAX threefry_partitionable=True, verified absmax 1.0 (rounds 1/6/7).
// Rotate as v_alignbit_b32 (1 op, bit-exact): rotl(x,r) = rotr(x, 32-r).
#define ROTL(x, r) __builtin_amdgcn_alignbit((x), (x), 32 - (r))

__device__ __forceinline__ uint2 tf2x32(uint32_t k0, uint32_t k1, uint32_t x0, uint32_t x1) {
  uint32_t k2 = k0 ^ k1 ^ 0x1BD11BDAu;
#define TFRND(r) { x0 += x1; x1 = ROTL(x1, r); x1 ^= x0; }
  x0 += k0; x1 += k1;
  TFRND(13) TFRND(15) TFRND(26) TFRND(6)
  x0 += k1; x1 += k2 + 1u;
  TFRND(17) TFRND(29) TFRND(16) TFRND(24)
  x0 += k2; x1 += k0 + 2u;
  TFRND(13) TFRND(15) TFRND(26) TFRND(6)
  x0 += k0; x1 += k1 + 3u;
  TFRND(17) TFRND(29) TFRND(16) TFRND(24)
  x0 += k1; x1 += k2 + 4u;
  TFRND(13) TFRND(15) TFRND(26) TFRND(6)
  x0 += k2; x1 += k0 + 5u;
#undef TFRND
  return make_uint2(x0, x1);
}

// One block per batch element n; all 32 scan steps fused; lq/sG/symbols in LDS.
__global__ __launch_bounds__(1024) void mfs_fused(
    const float* __restrict__ log_qi, const float* __restrict__ G,
    const float* __restrict__ s2r, const float* __restrict__ alpha_p,
    float* __restrict__ lq_out) {
  __shared__ float sg[NM * NT];          // 8 KiB
  __shared__ float lqs[NT * LQP];        // padded 32x9 dwords
  __shared__ uint8_t symu[NS * SYP];     // padded 256x36 bytes (u8 = sym+7)
  __shared__ double red[16][NK];         // wave partials
  __shared__ uint32_t keys2[NT * 2];

  const int n = blockIdx.x;
  const int tid = threadIdx.x;

  {
    float s2v = s2r[n];
    float2 g2 = ((const float2*)(G + (size_t)n * NM * NT))[tid];
    ((float2*)sg)[tid] = make_float2(s2v * g2.x, s2v * g2.y);   // exact f32 mul
  }
  if (tid < NT * NK) lqs[(tid >> 3) * LQP + (tid & 7)] = log_qi[(size_t)n * NT * NK + tid];
  if (tid < NT) {
    // split foldlike: key_i = threefry2x32(parent=(0,42), hi=0, lo=i)
    uint2 r = tf2x32(0u, 42u, 0u, (uint32_t)tid);
    keys2[2 * tid] = r.x; keys2[2 * tid + 1] = r.y;
  }
  __syncthreads();

  const float alpha = *alpha_p;
  const int t = tid & 31;            // sampling: antenna owned by this thread
  const int sgrp = tid >> 5;         // sampling: s-group 0..31
  const int ss = tid & 255;          // update: sample row
  const int mg = tid >> 8;           // update: m-group 0..3 (16 m's each)

  for (int xi = 0; xi < NT; ++xi) {
    // ---------- sample: 8 draws/thread ----------
    // argmax_k(l[k] + g_k), g = -log(-log(u))  <=>  argmin_k e_k * exp(-l[k]),
    // e_k = -log(u_k): strictly-monotone transform; first-extreme tie-break
    // preserved by strict <. Any symbol that can win has l >= -21.2 so
    // E = exp(-l) <= 1.6e9 stays finite; overflow only hits never-winners.
    uint32_t kA = keys2[2 * xi], kB = keys2[2 * xi + 1];
    float E[NK];
#pragma unroll
    for (int k = 0; k < NK; ++k) E[k] = __expf(-lqs[t * LQP + k]);
    const float TINY = 1.17549435e-38f;
    for (int d = 0; d < 8; ++d) {
      int s = sgrp + (d << 5);
      uint32_t p = ((uint32_t)((s * NB + n) * NT + t)) << 3; // flat (S,N,T,K) index
      float best = INFINITY; int bi = 0;
#pragma unroll
      for (int k = 0; k < NK; ++k) {
        uint2 r = tf2x32(kA, kB, 0u, p + (uint32_t)k);
        uint32_t bits = r.x ^ r.y;
        float f = __uint_as_float((bits >> 9) | 0x3f800000u) - 1.0f;
        float u = fmaxf(TINY, f + TINY);          // JAX uniform(tiny, 1)
        float e = -__logf(u);                     // v_log-based
        float score = e * E[k];
        if (score < best) { best = score; bi = k; }
      }
      symu[s * SYP + t] = (uint8_t)(2 * bi);                 // u8 = sym + 7
    }
    __syncthreads();

    // ---------- update: thread = (sample ss, m-group mg) ----------
    uint32_t w[8];
#pragma unroll
    for (int j = 0; j < 8; ++j) w[j] = *(const uint32_t*)(symu + ss * SYP + 4 * j);
    {
      int jx = xi >> 2;
      uint32_t sh = (uint32_t)(8 * (xi & 3));
      uint32_t mask = 0xffu << sh, ins = 7u << sh;           // u=7 <=> symbol 0
#pragma unroll
      for (int j = 0; j < 8; ++j)
        w[j] = (j == jx) ? ((w[j] & ~mask) | ins) : w[j];    // static idx, cndmask
    }
    // dot products: j-outer so each w[j] is converted ONCE (was 16x).
    // Per-acc[mi] FMA order identical to round 7 (j ascending, xyzw) -> bit-exact.
    const float* sgp = sg + mg * 16 * NT;
    float acc[16];
#pragma unroll
    for (int mi = 0; mi < 16; ++mi) acc[mi] = 0.0f;
#pragma unroll
    for (int j = 0; j < 8; ++j) {
      float s0 = (float)( w[j]        & 0xffu) - 7.0f;       // v_cvt_f32_ubyte0..3
      float s1 = (float)((w[j] >>  8) & 0xffu) - 7.0f;
      float s2 = (float)((w[j] >> 16) & 0xffu) - 7.0f;
      float s3 = (float)( w[j] >> 24         ) - 7.0f;
#pragma unroll
      for (int mi = 0; mi < 16; ++mi) {
        float4 g4 = ((const float4*)(sgp + mi * NT))[j];     // wave-uniform
        acc[mi] = fmaf(g4.x, s0, acc[mi]);
        acc[mi] = fmaf(g4.y, s1, acc[mi]);
        acc[mi] = fmaf(g4.z, s2, acc[mi]);
        acc[mi] = fmaf(g4.w, s3, acc[mi]);
      }
    }
    float lp[NK];
#pragma unroll
    for (int k = 0; k < NK; ++k) lp[k] = 0.0f;
#pragma unroll
    for (int mi = 0; mi < 16; ++mi) {
      float base = acc[mi];
      float c = sgp[mi * NT + xi];
#pragma unroll
      for (int k = 0; k < NK; ++k) {
        float term = fmaf(c, (float)(2 * k - 7), base);
        float z = 1.702f * term;
        // log_sigmoid via fast intrinsics — proven safe (round 7, absmax 1.0)
        float az = fabsf(z);
        float e = __expf(-az);
        lp[k] += fminf(z, 0.0f) - __logf(1.0f + e);
      }
    }

    // reduction: IDENTICAL structure/order to rounds 6/7 (proven absmax 1.0)
    double v[NK];
#pragma unroll
    for (int k = 0; k < NK; ++k) v[k] = (double)lp[k];
#pragma unroll
    for (int off = 32; off >= 1; off >>= 1) {
#pragma unroll
      for (int k = 0; k < NK; ++k) v[k] += __shfl_down(v[k], off, 64);
    }
    int wave = tid >> 6, lane = tid & 63;
    if (lane == 0) {
#pragma unroll
      for (int k = 0; k < NK; ++k) red[wave][k] = v[k];
    }
    __syncthreads();
    if (tid < NK) {
      double sum = 0.0;
#pragma unroll
      for (int q = 0; q < 16; ++q) sum += red[q][tid];
      float ex = (float)(sum * (1.0 / 256.0));
      float oldv = lqs[xi * LQP + tid];
      lqs[xi * LQP + tid] = (1.0f - alpha) * oldv + alpha * ex;
    }
    __syncthreads();
    if (tid < NT * NK) {
      // per-row max shift (exact; settled rows have max==0 -> bit-exact no-op)
      int t2 = tid >> 3, k2 = tid & 7;
      float vv = lqs[t2 * LQP + k2];
      float mx = vv;
      mx = fmaxf(mx, __shfl_xor(mx, 1, 64));
      mx = fmaxf(mx, __shfl_xor(mx, 2, 64));
      mx = fmaxf(mx, __shfl_xor(mx, 4, 64));
      lqs[t2 * LQP + k2] = vv - mx;
    }
    __syncthreads();
  }

  if (tid < NT * NK)
    lq_out[(size_t)n * NT * NK + tid] = lqs[(tid >> 3) * LQP + (tid & 7)];
}

extern "C" void kernel_launch(void* const* d_in, const int* in_sizes, int n_in,
                              void* d_out, int out_size, void* d_ws, size_t ws_size,
                              hipStream_t stream) {
  const float* log_qi = (const float*)d_in[0];
  const float* G      = (const float*)d_in[1];
  const float* s2r    = (const float*)d_in[2];
  const float* alpha  = (const float*)d_in[3];
  float* lq = (float*)d_out;
  mfs_fused<<<NB, 1024, 0, stream>>>(log_qi, G, s2r, alpha, lq);
}

// Round 10
// 3699.720 us; speedup vs baseline: 2.5235x; 1.0048x over previous
//
#include <hip/hip_runtime.h>
#include <stdint.h>

// Problem dims
#define NB 512   // batch N
#define NM 64    // rows of G
#define NT 32    // tx antennas (and scan steps)
#define NK 8     // symbol alphabet
#define NS 256   // MC samples
#define LQP 9    // padded LDS row stride for lq (dwords)
#define SYP 36   // padded LDS row stride for sym (bytes)

// JAX threefry_partitionable=True, verified absmax 1.0 (rounds 1/6/7/8).
// Rotate as v_alignbit_b32 (1 op, bit-exact): rotl(x,r) = rotr(x, 32-r).
#define ROTL(x, r) __builtin_amdgcn_alignbit((x), (x), 32 - (r))

__device__ __forceinline__ uint2 tf2x32(uint32_t k0, uint32_t k1, uint32_t x0, uint32_t x1) {
  uint32_t k2 = k0 ^ k1 ^ 0x1BD11BDAu;
#define TFRND(r) { x0 += x1; x1 = ROTL(x1, r); x1 ^= x0; }
  x0 += k0; x1 += k1;
  TFRND(13) TFRND(15) TFRND(26) TFRND(6)
  x0 += k1; x1 += k2 + 1u;
  TFRND(17) TFRND(29) TFRND(16) TFRND(24)
  x0 += k2; x1 += k0 + 2u;
  TFRND(13) TFRND(15) TFRND(26) TFRND(6)
  x0 += k0; x1 += k1 + 3u;
  TFRND(17) TFRND(29) TFRND(16) TFRND(24)
  x0 += k1; x1 += k2 + 4u;
  TFRND(13) TFRND(15) TFRND(26) TFRND(6)
  x0 += k2; x1 += k0 + 5u;
#undef TFRND
  return make_uint2(x0, x1);
}

// One block per batch element n; all 32 scan steps fused; lq/sG/symbols in LDS.
// __launch_bounds__(1024, 4): exactly one resident 16-wave block per CU (what
// rocprof shows anyway at 48% occupancy) -> licenses 128 VGPRs instead of the
// allocator's 48-VGPR squeeze (round 8), letting LDS reads batch ahead.
__global__ __launch_bounds__(1024, 4) void mfs_fused(
    const float* __restrict__ log_qi, const float* __restrict__ G,
    const float* __restrict__ s2r, const float* __restrict__ alpha_p,
    float* __restrict__ lq_out) {
  __shared__ float sg[NM * NT];          // 8 KiB
  __shared__ float lqs[NT * LQP];        // padded 32x9 dwords
  __shared__ uint8_t symu[NS * SYP];     // padded 256x36 bytes (u8 = sym+7)
  __shared__ double red[16][NK];         // wave partials
  __shared__ uint32_t keys2[NT * 2];

  const int n = blockIdx.x;
  const int tid = threadIdx.x;

  {
    float s2v = s2r[n];
    float2 g2 = ((const float2*)(G + (size_t)n * NM * NT))[tid];
    ((float2*)sg)[tid] = make_float2(s2v * g2.x, s2v * g2.y);   // exact f32 mul
  }
  if (tid < NT * NK) lqs[(tid >> 3) * LQP + (tid & 7)] = log_qi[(size_t)n * NT * NK + tid];
  if (tid < NT) {
    // split foldlike: key_i = threefry2x32(parent=(0,42), hi=0, lo=i)
    uint2 r = tf2x32(0u, 42u, 0u, (uint32_t)tid);
    keys2[2 * tid] = r.x; keys2[2 * tid + 1] = r.y;
  }
  __syncthreads();

  // Init-shift rows 1..31 once. In the reference, row r's shift first applies at
  // the END of step 0; afterwards re-shifts are bit-exact no-ops (max==0). Row r's
  // own update (step r>0) sees the shifted value -> same bits. Row 0's step-0
  // oldv must be the ORIGINAL unshifted value, so skip it here; sampling is
  // shift-invariant (uniform score scale, order-preserving mod rounding).
  if (tid < NT * NK) {
    int t2 = tid >> 3;
    float vv = lqs[t2 * LQP + (tid & 7)];
    float mx = vv;
    mx = fmaxf(mx, __shfl_xor(mx, 1, 64));
    mx = fmaxf(mx, __shfl_xor(mx, 2, 64));
    mx = fmaxf(mx, __shfl_xor(mx, 4, 64));
    if (t2 > 0) lqs[t2 * LQP + (tid & 7)] = vv - mx;
  }
  __syncthreads();

  const float alpha = *alpha_p;
  const int t = tid & 31;            // sampling: antenna owned by this thread
  const int sgrp = tid >> 5;         // sampling: s-group 0..31
  const int ss = tid & 255;          // update: sample row
  const int mg = tid >> 8;           // update: m-group 0..3 (16 m's each)
  const float TINY = 1.17549435e-38f;
  const float K2 = 2.4554669595930158f;   // 1.702 * log2(e)

  for (int xi = 0; xi < NT; ++xi) {
    // ---------- sample: 8 draws/thread ----------
    // argmax_k(l+g), g=-log(-log(u))  <=>  argmin_k (-ln u)*exp(-l)
    //  = argmin_k log2(u) * F[k],  F[k] = -ln2 * exp(-l[k])  (score >= 0).
    // Packed-uint argmin: scores >= 0 so float bits are uint-monotone; low 3
    // bits carry k; min_u32 keeps first-max tie-break (smaller k wins ties).
    uint32_t kA = keys2[2 * xi], kB = keys2[2 * xi + 1];
    float F[NK];
#pragma unroll
    for (int k = 0; k < NK; ++k) {
      float l = lqs[t * LQP + k];
      float E = __expf(fminf(-l, 80.0f));   // clamp: junk symbols stay finite
      F[k] = -0.69314718055994531f * E;
    }
    for (int d = 0; d < 8; ++d) {
      int s = sgrp + (d << 5);
      uint32_t p = ((uint32_t)((s * NB + n) * NT + t)) << 3;  // flat (S,N,T,K)
      uint32_t best = 0xffffffffu;
#pragma unroll
      for (int k = 0; k < NK; ++k) {
        uint2 r = tf2x32(kA, kB, 0u, p + (uint32_t)k);
        uint32_t bits = r.x ^ r.y;
        float f = __uint_as_float((bits >> 9) | 0x3f800000u) - 1.0f;
        float u = fmaxf(f, TINY);           // == fmax(TINY, f+TINY) bit-exact
        float score = __log2f(u) * F[k];    // v_log + v_mul, >= 0
        uint32_t sv = (__float_as_uint(score) & ~7u) | (uint32_t)k;
        best = min(best, sv);
      }
      symu[s * SYP + t] = (uint8_t)((best & 7u) << 1);        // u8 = 2*argmax
    }
    __syncthreads();

    // ---------- update: thread = (sample ss, m-group mg) ----------
    uint32_t w[8];
#pragma unroll
    for (int j = 0; j < 8; ++j) w[j] = *(const uint32_t*)(symu + ss * SYP + 4 * j);
    {
      int jx = xi >> 2;
      uint32_t sh = (uint32_t)(8 * (xi & 3));
      uint32_t mask = 0xffu << sh, ins = 7u << sh;            // u=7 <=> symbol 0
#pragma unroll
      for (int j = 0; j < 8; ++j)
        w[j] = (j == jx) ? ((w[j] & ~mask) | ins) : w[j];     // static idx, cndmask
    }
    // dot products: j-outer, each w[j] converted once; per-acc[mi] FMA order
    // identical to rounds 7/8 (j ascending, xyzw) -> bit-exact chain.
    const float* sgp = sg + mg * 16 * NT;
    float acc[16];
#pragma unroll
    for (int mi = 0; mi < 16; ++mi) acc[mi] = 0.0f;
#pragma unroll
    for (int j = 0; j < 8; ++j) {
      float s0 = (float)( w[j]        & 0xffu) - 7.0f;        // v_cvt_f32_ubyte
      float s1 = (float)((w[j] >>  8) & 0xffu) - 7.0f;
      float s2 = (float)((w[j] >> 16) & 0xffu) - 7.0f;
      float s3 = (float)( w[j] >> 24         ) - 7.0f;
#pragma unroll
      for (int mi = 0; mi < 16; ++mi) {
        float4 g4 = ((const float4*)(sgp + mi * NT))[j];      // wave-uniform
        acc[mi] = fmaf(g4.x, s0, acc[mi]);
        acc[mi] = fmaf(g4.y, s1, acc[mi]);
        acc[mi] = fmaf(g4.z, s2, acc[mi]);
        acc[mi] = fmaf(g4.w, s3, acc[mi]);
      }
    }
    // log-sigmoid in log2 domain: ls(z)/ln2 = min(zb,0) - log2(1+exp2(-|zb|)),
    // zb = term*K2. ln2 folded into the final mean constant. exp2f/__log2f are
    // single v_exp_f32/v_log_f32 on gfx950 (base-2 is the HW native).
    float lp[NK];
#pragma unroll
    for (int k = 0; k < NK; ++k) lp[k] = 0.0f;
#pragma unroll
    for (int mi = 0; mi < 16; ++mi) {
      float base2 = acc[mi] * K2;
      float c2 = sgp[mi * NT + xi] * K2;
#pragma unroll
      for (int k = 0; k < NK; ++k) {
        float zb = fmaf(c2, (float)(2 * k - 7), base2);
        float e2 = exp2f(-fabsf(zb));                         // v_exp_f32
        lp[k] += fminf(zb, 0.0f) - __log2f(1.0f + e2);
      }
    }

    // reduction: f64 tree, structure/order identical to rounds 6/7/8 (proven)
    double v[NK];
#pragma unroll
    for (int k = 0; k < NK; ++k) v[k] = (double)lp[k];
#pragma unroll
    for (int off = 32; off >= 1; off >>= 1) {
#pragma unroll
      for (int k = 0; k < NK; ++k) v[k] += __shfl_down(v[k], off, 64);
    }
    int wave = tid >> 6, lane = tid & 63;
    if (lane == 0) {
#pragma unroll
      for (int k = 0; k < NK; ++k) red[wave][k] = v[k];
    }
    __syncthreads();
    if (tid < NK) {
      double sum = 0.0;
#pragma unroll
      for (int q = 0; q < 16; ++q) sum += red[q][tid];
      float ex = (float)(sum * 0.0027076061740622863);        // ln2/256
      float oldv = lqs[xi * LQP + tid];
      float newv = (1.0f - alpha) * oldv + alpha * ex;
      // per-row max shift for the just-updated row (lanes 0..7, in-register)
      float mx = newv;
      mx = fmaxf(mx, __shfl_xor(mx, 1, 64));
      mx = fmaxf(mx, __shfl_xor(mx, 2, 64));
      mx = fmaxf(mx, __shfl_xor(mx, 4, 64));
      lqs[xi * LQP + tid] = newv - mx;
    }
    __syncthreads();
  }

  if (tid < NT * NK)
    lq_out[(size_t)n * NT * NK + tid] = lqs[(tid >> 3) * LQP + (tid & 7)];
}

extern "C" void kernel_launch(void* const* d_in, const int* in_sizes, int n_in,
                              void* d_out, int out_size, void* d_ws, size_t ws_size,
                              hipStream_t stream) {
  const float* log_qi = (const float*)d_in[0];
  const float* G      = (const float*)d_in[1];
  const float* s2r    = (const float*)d_in[2];
  const float* alpha  = (const float*)d_in[3];
  float* lq = (float*)d_out;
  mfs_fused<<<NB, 1024, 0, stream>>>(log_qi, G, s2r, alpha, lq);
}

// Round 11
// 2698.027 us; speedup vs baseline: 3.4603x; 1.3713x over previous
//
#include <hip/hip_runtime.h>
#include <stdint.h>

// Problem dims
#define NB 512   // batch N
#define NM 64    // rows of G
#define NT 32    // tx antennas (and scan steps)
#define NK 8     // symbol alphabet
#define NS 256   // MC samples
#define LQP 9    // padded LDS row stride for lq (dwords)
#define SYF 36   // float stride for symbol rows (144B: 16B-aligned -> b128 reads)

// JAX threefry_partitionable=True, verified absmax 1.0 (rounds 1/6/7/8/10).
// Rotate as v_alignbit_b32 (1 op, bit-exact): rotl(x,r) = rotr(x, 32-r).
#define ROTL(x, r) __builtin_amdgcn_alignbit((x), (x), 32 - (r))

// Raw HW transcendentals (v_exp_f32 / v_log_f32 are base-2 on gfx950).
#if __has_builtin(__builtin_amdgcn_exp2f)
#define EXP2(x) __builtin_amdgcn_exp2f(x)
#else
#define EXP2(x) exp2f(x)
#endif
#if __has_builtin(__builtin_amdgcn_logf)
#define LOG2(x) __builtin_amdgcn_logf(x)
#else
#define LOG2(x) __log2f(x)
#endif

__device__ __forceinline__ uint2 tf2x32(uint32_t k0, uint32_t k1, uint32_t x0, uint32_t x1) {
  uint32_t k2 = k0 ^ k1 ^ 0x1BD11BDAu;
#define TFRND(r) { x0 += x1; x1 = ROTL(x1, r); x1 ^= x0; }
  x0 += k0; x1 += k1;
  TFRND(13) TFRND(15) TFRND(26) TFRND(6)
  x0 += k1; x1 += k2 + 1u;
  TFRND(17) TFRND(29) TFRND(16) TFRND(24)
  x0 += k2; x1 += k0 + 2u;
  TFRND(13) TFRND(15) TFRND(26) TFRND(6)
  x0 += k0; x1 += k1 + 3u;
  TFRND(17) TFRND(29) TFRND(16) TFRND(24)
  x0 += k1; x1 += k2 + 4u;
  TFRND(13) TFRND(15) TFRND(26) TFRND(6)
  x0 += k2; x1 += k0 + 5u;
#undef TFRND
  return make_uint2(x0, x1);
}

// One block per batch element n; all 32 scan steps fused; everything in LDS.
// min-waves=8: VGPR need is ~40-48 (fits the 64 budget without spilling, unlike
// round 6's old structure) -> 2 blocks/CU resident, covering barrier drains.
__global__ __launch_bounds__(1024, 8) void mfs_fused(
    const float* __restrict__ log_qi, const float* __restrict__ G,
    const float* __restrict__ s2r, const float* __restrict__ alpha_p,
    float* __restrict__ lq_out) {
  __shared__ float sg[NM * NT];          // 8 KiB
  __shared__ float lqs[NT * LQP];        // padded 32x9 dwords
  __shared__ float symf[NS * SYF];       // 36 KiB: symbols as floats, xi-col = 0
  __shared__ double red[16][NK];         // wave partials
  __shared__ uint32_t keys2[NT * 2];

  const int n = blockIdx.x;
  const int tid = threadIdx.x;

  {
    float s2v = s2r[n];
    float2 g2 = ((const float2*)(G + (size_t)n * NM * NT))[tid];
    ((float2*)sg)[tid] = make_float2(s2v * g2.x, s2v * g2.y);   // exact f32 mul
  }
  if (tid < NT * NK) lqs[(tid >> 3) * LQP + (tid & 7)] = log_qi[(size_t)n * NT * NK + tid];
  if (tid < NT) {
    // split foldlike: key_i = threefry2x32(parent=(0,42), hi=0, lo=i)
    uint2 r = tf2x32(0u, 42u, 0u, (uint32_t)tid);
    keys2[2 * tid] = r.x; keys2[2 * tid + 1] = r.y;
  }
  __syncthreads();

  // Init-shift rows 1..31 once (row r's shift first applies at end of step 0 in
  // the reference; re-shifts of settled rows are bit-exact no-ops). Row 0's
  // step-0 oldv must stay unshifted. Sampling is shift-invariant.
  if (tid < NT * NK) {
    int t2 = tid >> 3;
    float vv = lqs[t2 * LQP + (tid & 7)];
    float mx = vv;
    mx = fmaxf(mx, __shfl_xor(mx, 1, 64));
    mx = fmaxf(mx, __shfl_xor(mx, 2, 64));
    mx = fmaxf(mx, __shfl_xor(mx, 4, 64));
    if (t2 > 0) lqs[t2 * LQP + (tid & 7)] = vv - mx;
  }
  __syncthreads();

  const float alpha = *alpha_p;
  const int t = tid & 31;            // sampling: antenna owned by this thread
  const int sgrp = tid >> 5;         // sampling: s-group 0..31
  const int ss = tid & 255;          // update: sample row
  const int mg = tid >> 8;           // update: m-group 0..3 (16 m's each)
  const float TINY = 1.17549435e-38f;
  const float K2 = 2.4554669595930158f;   // 1.702 * log2(e)

  for (int xi = 0; xi < NT; ++xi) {
    // ---------- sample: 8 draws/thread ----------
    // argmax_k(l+g), g=-log(-log(u))  <=>  argmin_k (-ln u)*exp(-l)
    //  = argmin_k (-log2 u) * Fp[k],  Fp[k] = ln2*exp(-l[k]) > 0 (score >= 0).
    // Fp = exp2(fma(l, -log2e, log2(ln2))). Packed-uint argmin keeps JAX's
    // first-max tie-break. No clamp needed: lg < 0 strictly, so inf*lg = inf
    // (never-winning symbols lose correctly; no 0*inf NaN possible).
    uint32_t kA = keys2[2 * xi], kB = keys2[2 * xi + 1];
    float Fp[NK];
#pragma unroll
    for (int k = 0; k < NK; ++k) {
      float l = lqs[t * LQP + k];
      Fp[k] = EXP2(fmaf(l, -1.4426950408889634f, -0.5287663729448977f));
    }
    bool isxi = (t == xi);
#pragma unroll
    for (int d = 0; d < 8; ++d) {
      int s = sgrp + (d << 5);
      uint32_t p = ((uint32_t)((s * NB + n) * NT + t)) << 3;  // flat (S,N,T,K)
      uint32_t best = 0xffffffffu;
#pragma unroll
      for (int k = 0; k < NK; ++k) {
        uint2 r = tf2x32(kA, kB, 0u, p + (uint32_t)k);
        uint32_t bits = r.x ^ r.y;
        float f = __uint_as_float((bits >> 9) | 0x3f800000u) - 1.0f;
        float u = fmaxf(f, TINY);           // == fmax(TINY, f+TINY) bit-exact
        float score = (-LOG2(u)) * Fp[k];   // neg folds into v_mul src modifier
        uint32_t sv = (__float_as_uint(score) & ~7u) | (uint32_t)k;
        best = min(best, sv);
      }
      // store symbol as float; antenna xi stores 0.0 (exclusion baked in; the
      // sampled value at (s, xi) is never used by this or any later step)
      float bi = (float)(int)(best & 7u);
      float symval = fmaf(bi, 2.0f, -7.0f);                   // 2*bi - 7, exact
      symf[s * SYF + t] = isxi ? 0.0f : symval;
    }
    __syncthreads();

    // ---------- update: thread = (sample ss, m-group mg) ----------
    // dot products: j-outer over t-quads; per-acc[mi] FMA order = t ascending,
    // bit-identical chain to round 10 (values identical: cvt moved to sampler).
    const float* sgp = sg + mg * 16 * NT;
    const float* myrow = symf + ss * SYF;
    float acc[16];
#pragma unroll
    for (int mi = 0; mi < 16; ++mi) acc[mi] = 0.0f;
#pragma unroll
    for (int j = 0; j < 8; ++j) {
      float4 sp4 = *(const float4*)(myrow + 4 * j);           // ds_read_b128
#pragma unroll
      for (int mi = 0; mi < 16; ++mi) {
        float4 g4 = ((const float4*)(sgp + mi * NT))[j];      // wave-uniform
        acc[mi] = fmaf(g4.x, sp4.x, acc[mi]);
        acc[mi] = fmaf(g4.y, sp4.y, acc[mi]);
        acc[mi] = fmaf(g4.z, sp4.z, acc[mi]);
        acc[mi] = fmaf(g4.w, sp4.w, acc[mi]);
      }
    }
    // log-sigmoid in log2 domain: ls(z)/ln2 = min(zb,0) - log2(1+exp2(-|zb|)),
    // zb = term*K2; ln2 folded into the final mean constant. EXP2/LOG2 are the
    // raw v_exp_f32/v_log_f32 (bit-identical to exp2f in our operand range).
    float lp[NK];
#pragma unroll
    for (int k = 0; k < NK; ++k) lp[k] = 0.0f;
#pragma unroll
    for (int mi = 0; mi < 16; ++mi) {
      float base2 = acc[mi] * K2;
      float c2 = sgp[mi * NT + xi] * K2;
#pragma unroll
      for (int k = 0; k < NK; ++k) {
        float zb = fmaf(c2, (float)(2 * k - 7), base2);
        float e2 = EXP2(-fabsf(zb));                          // -|x| src mods
        lp[k] += fminf(zb, 0.0f) - LOG2(1.0f + e2);
      }
    }

    // reduction: f64 tree, structure/order identical to rounds 6-10 (proven)
    double v[NK];
#pragma unroll
    for (int k = 0; k < NK; ++k) v[k] = (double)lp[k];
#pragma unroll
    for (int off = 32; off >= 1; off >>= 1) {
#pragma unroll
      for (int k = 0; k < NK; ++k) v[k] += __shfl_down(v[k], off, 64);
    }
    int wave = tid >> 6, lane = tid & 63;
    if (lane == 0) {
#pragma unroll
      for (int k = 0; k < NK; ++k) red[wave][k] = v[k];
    }
    __syncthreads();
    if (tid < NK) {
      double sum = 0.0;
#pragma unroll
      for (int q = 0; q < 16; ++q) sum += red[q][tid];
      float ex = (float)(sum * 0.0027076061740622863);        // ln2/256
      float oldv = lqs[xi * LQP + tid];
      float newv = (1.0f - alpha) * oldv + alpha * ex;
      // per-row max shift for the just-updated row (lanes 0..7, in-register)
      float mx = newv;
      mx = fmaxf(mx, __shfl_xor(mx, 1, 64));
      mx = fmaxf(mx, __shfl_xor(mx, 2, 64));
      mx = fmaxf(mx, __shfl_xor(mx, 4, 64));
      lqs[xi * LQP + tid] = newv - mx;
    }
    __syncthreads();
  }

  if (tid < NT * NK)
    lq_out[(size_t)n * NT * NK + tid] = lqs[(tid >> 3) * LQP + (tid & 7)];
}

extern "C" void kernel_launch(void* const* d_in, const int* in_sizes, int n_in,
                              void* d_out, int out_size, void* d_ws, size_t ws_size,
                              hipStream_t stream) {
  const float* log_qi = (const float*)d_in[0];
  const float* G      = (const float*)d_in[1];
  const float* s2r    = (const float*)d_in[2];
  const float* alpha  = (const float*)d_in[3];
  float* lq = (float*)d_out;
  mfs_fused<<<NB, 1024, 0, stream>>>(log_qi, G, s2r, alpha, lq);
}